// Round 8
// baseline (723.741 us; speedup 1.0000x reference)
//
#include <hip/hip_runtime.h>
#include <hip/hip_bf16.h>

// B=4, S=2048, D=1024, H=16, DK=DV=64.
// CONFIRMED (r6 NaN + r7 probe): inputs f32, output f32 (read as f32;
// threshold = 2% x max|ref|). MFMA math in bf16 with f32 accumulation;
// final store f32. Workspace peak 24 MB (< proven 29 MB bound).

typedef __attribute__((ext_vector_type(8))) short bf16x8;
typedef __attribute__((ext_vector_type(4))) float f32x4;
typedef __attribute__((ext_vector_type(4))) unsigned int u32x4;

#define MFMA16(a, b, c) __builtin_amdgcn_mfma_f32_16x16x32_bf16((a), (b), (c), 0, 0, 0)

#define LOG2E 1.44269504088896340736f
#define BIG_NEG (-3.0e38f)

__device__ __forceinline__ unsigned short f2bf(float f) {
  union { float f; unsigned int i; } x; x.f = f;
  unsigned int lsb = (x.i >> 16) & 1;
  x.i += 0x7fffu + lsb;  // RNE (finite inputs only)
  return (unsigned short)(x.i >> 16);
}
__device__ __forceinline__ float bf2f(unsigned short u) {
  union { unsigned int i; float f; } x; x.i = ((unsigned int)u) << 16; return x.f;
}

// ---------------------------------------------------------------------------
// Batched transpose + downconvert: in f32 [batch][R][C] -> out bf16 [batch][C][R]
// ---------------------------------------------------------------------------
__global__ void wtrans_kernel(const float* __restrict__ in,
                              unsigned short* __restrict__ out, int R, int C) {
  __shared__ unsigned short tile[32][33];
  const int bz = blockIdx.z;
  const int c0 = blockIdx.x * 32, r0 = blockIdx.y * 32;
  const float* ip = in + (size_t)bz * R * C;
  unsigned short* op = out + (size_t)bz * R * C;
  const int tx = threadIdx.x, ty = threadIdx.y;  // (32, 8)
#pragma unroll
  for (int i = 0; i < 32; i += 8)
    tile[ty + i][tx] = f2bf(ip[(size_t)(r0 + ty + i) * C + (c0 + tx)]);
  __syncthreads();
#pragma unroll
  for (int i = 0; i < 32; i += 8)
    op[(size_t)(c0 + ty + i) * R + (r0 + tx)] = tile[tx][ty + i];
}

// ---------------------------------------------------------------------------
// QKV projection for ONE batch: embB f32 [2048][1024] x WtT bf16 [h][c][d] ->
// Q,K bf16 [h][s][64], V transposed -> Vt [h][dv][s] (swapped-operand MFMA).
// Tile: 128(M) x 128(N), BK=32, 4 waves, each wave 64x64 (4x4 MFMA accs).
// emb converted f32->bf16 on the fly during LDS staging.
// ---------------------------------------------------------------------------
__global__ __launch_bounds__(256)
void qkv_kernel(const float* __restrict__ embB,
                const unsigned short* __restrict__ WqT,
                const unsigned short* __restrict__ WkT,
                const unsigned short* __restrict__ WvT,
                unsigned short* __restrict__ Qh,
                unsigned short* __restrict__ Kh,
                unsigned short* __restrict__ Vth) {
  const int t = blockIdx.z;           // 0=Q, 1=K, 2=V
  const int m0 = blockIdx.y * 128;    // row in [0, 2048)
  const int n0 = blockIdx.x * 128;    // col in [0, 1024) -> heads n0/64, n0/64+1
  const unsigned short* Wt =
      (t == 0 ? WqT : (t == 1 ? WkT : WvT)) + (size_t)(n0 >> 6) * 64 * 1024;

  __shared__ __align__(16) unsigned short As[128][40];  // [m][k], +8 pad
  __shared__ __align__(16) unsigned short Bs[128][40];  // [n][k]

  const int tid = threadIdx.x;
  const int lane = tid & 63, w = tid >> 6;
  const int q4 = lane >> 4, l16 = lane & 15;
  const int arow = tid >> 1, acol = (tid & 1) * 16;

  f32x4 acc[4][4] = {};

  for (int k0 = 0; k0 < 1024; k0 += 32) {
    __syncthreads();
    {
      const float* erow = &embB[(size_t)(m0 + arow) * 1024 + k0 + acol];
      const float4 v0 = *(const float4*)&erow[0];
      const float4 v1 = *(const float4*)&erow[4];
      const float4 v2 = *(const float4*)&erow[8];
      const float4 v3 = *(const float4*)&erow[12];
      union { unsigned short u[8]; u32x4 v; } p0, p1;
      p0.u[0] = f2bf(v0.x); p0.u[1] = f2bf(v0.y); p0.u[2] = f2bf(v0.z); p0.u[3] = f2bf(v0.w);
      p0.u[4] = f2bf(v1.x); p0.u[5] = f2bf(v1.y); p0.u[6] = f2bf(v1.z); p0.u[7] = f2bf(v1.w);
      p1.u[0] = f2bf(v2.x); p1.u[1] = f2bf(v2.y); p1.u[2] = f2bf(v2.z); p1.u[3] = f2bf(v2.w);
      p1.u[4] = f2bf(v3.x); p1.u[5] = f2bf(v3.y); p1.u[6] = f2bf(v3.z); p1.u[7] = f2bf(v3.w);
      *(u32x4*)&As[arow][acol]     = p0.v;
      *(u32x4*)&As[arow][acol + 8] = p1.v;
    }
    *(u32x4*)&Bs[arow][acol]     = *(const u32x4*)&Wt[(size_t)arow * 1024 + k0 + acol];
    *(u32x4*)&Bs[arow][acol + 8] = *(const u32x4*)&Wt[(size_t)arow * 1024 + k0 + acol + 8];
    __syncthreads();

    // t==2: compute (W^T * emb^T) = V^T directly by swapping operand roles.
    const unsigned short (*PA)[40] = (t == 2) ? Bs : As;
    const unsigned short (*PB)[40] = (t == 2) ? As : Bs;

    bf16x8 af[4], bfr[4];
#pragma unroll
    for (int ms = 0; ms < 4; ++ms)
      af[ms] = *(const bf16x8*)&PA[(w >> 1) * 64 + ms * 16 + l16][q4 * 8];
#pragma unroll
    for (int js = 0; js < 4; ++js)
      bfr[js] = *(const bf16x8*)&PB[(w & 1) * 64 + js * 16 + l16][q4 * 8];
#pragma unroll
    for (int ms = 0; ms < 4; ++ms)
#pragma unroll
      for (int js = 0; js < 4; ++js)
        acc[ms][js] = MFMA16(af[ms], bfr[js], acc[ms][js]);
  }

  if (t < 2) {
    unsigned short* outp = (t == 0) ? Qh : Kh;
    const int h = (n0 >> 6) + (w & 1);
    const size_t hb = (size_t)h * 2048;
#pragma unroll
    for (int ms = 0; ms < 4; ++ms)
#pragma unroll
      for (int js = 0; js < 4; ++js) {
        const int c = js * 16 + l16;
#pragma unroll
        for (int r = 0; r < 4; ++r) {
          const int s = m0 + (w >> 1) * 64 + ms * 16 + q4 * 4 + r;
          outp[(hb + s) * 64 + c] = f2bf(acc[ms][js][r]);
        }
      }
  } else {
    const int h = (n0 >> 6) + (w >> 1);
    const size_t hb = (size_t)h * 64;
#pragma unroll
    for (int ms = 0; ms < 4; ++ms)
#pragma unroll
      for (int js = 0; js < 4; ++js) {
        const int s = m0 + (w & 1) * 64 + js * 16 + l16;
#pragma unroll
        for (int r = 0; r < 4; ++r) {
          const int c = ms * 16 + q4 * 4 + r;
          Vth[(hb + c) * 2048 + s] = f2bf(acc[ms][js][r]);
        }
      }
  }
}

// ---------------------------------------------------------------------------
// Flash attention, causal, ONE batch. Block = (q-tile of 64 rows, head).
// Each wave owns 16 q-rows. K/Vt tiles staged in LDS; Q frags in regs;
// P round-trips through per-wave LDS (C-layout -> A-layout).
// ---------------------------------------------------------------------------
__global__ __launch_bounds__(256)
void flash_kernel(const unsigned short* __restrict__ Qh,
                  const unsigned short* __restrict__ Kh,
                  const unsigned short* __restrict__ Vth,
                  unsigned short* __restrict__ ObB) {
  const int h = blockIdx.y;
  const int qt = (gridDim.x - 1) - blockIdx.x;  // longest blocks dispatch first
  const int q0 = qt * 64;
  const int tid = threadIdx.x;
  const int lane = tid & 63, w = tid >> 6;
  const int q4 = lane >> 4, l16 = lane & 15;

  const unsigned short* Qp = Qh + ((size_t)h * 2048 + q0 + w * 16) * 64;
  const unsigned short* Kp = Kh + (size_t)h * 2048 * 64;
  const unsigned short* Vp = Vth + (size_t)h * 64 * 2048;

  const bf16x8 qf0 = *(const bf16x8*)&Qp[(size_t)l16 * 64 + q4 * 8];
  const bf16x8 qf1 = *(const bf16x8*)&Qp[(size_t)l16 * 64 + 32 + q4 * 8];

  __shared__ __align__(16) unsigned short Ks[64][72];        // [s][d]
  __shared__ __align__(16) unsigned short Vs[64][72];        // [dv][s]
  __shared__ __align__(16) unsigned short Plds[4][16][72];   // per-wave P round-trip

  f32x4 oacc[4] = {};
  float m_i[4], l_i[4];
#pragma unroll
  for (int r = 0; r < 4; ++r) { m_i[r] = BIG_NEG; l_i[r] = 0.f; }

  const float sscale = 0.125f * LOG2E;  // softmax in exp2 domain

  for (int j0 = 0; j0 <= q0; j0 += 64) {
    __syncthreads();
#pragma unroll
    for (int i = 0; i < 2; ++i) {
      const int r = (tid >> 3) + i * 32, c = (tid & 7) * 8;
      *(u32x4*)&Ks[r][c] = *(const u32x4*)&Kp[(size_t)(j0 + r) * 64 + c];
      *(u32x4*)&Vs[r][c] = *(const u32x4*)&Vp[(size_t)r * 2048 + j0 + c];
    }
    __syncthreads();

    // S = Q K^T for 16 q-rows x 64 k-cols
    f32x4 sacc[4] = {};
#pragma unroll
    for (int js = 0; js < 4; ++js) {
      const bf16x8 kf0 = *(const bf16x8*)&Ks[js * 16 + l16][q4 * 8];
      const bf16x8 kf1 = *(const bf16x8*)&Ks[js * 16 + l16][32 + q4 * 8];
      sacc[js] = MFMA16(qf0, kf0, sacc[js]);
      sacc[js] = MFMA16(qf1, kf1, sacc[js]);
    }

    float mloc[4];
#pragma unroll
    for (int r = 0; r < 4; ++r) mloc[r] = BIG_NEG;
    if (j0 == q0) {
#pragma unroll
      for (int js = 0; js < 4; ++js) {
        const int col = js * 16 + l16;
#pragma unroll
        for (int r = 0; r < 4; ++r) {
          const int qrel = w * 16 + q4 * 4 + r;
          float v = sacc[js][r] * sscale;
          if (col > qrel) v = BIG_NEG;
          sacc[js][r] = v;
          mloc[r] = fmaxf(mloc[r], v);
        }
      }
    } else {
#pragma unroll
      for (int js = 0; js < 4; ++js)
#pragma unroll
        for (int r = 0; r < 4; ++r) {
          const float v = sacc[js][r] * sscale;
          sacc[js][r] = v;
          mloc[r] = fmaxf(mloc[r], v);
        }
    }

    // row max/sum across the 16 lanes sharing q4
#pragma unroll
    for (int d = 1; d < 16; d <<= 1)
#pragma unroll
      for (int r = 0; r < 4; ++r)
        mloc[r] = fmaxf(mloc[r], __shfl_xor(mloc[r], d, 64));

    float alpha[4], rsum[4];
#pragma unroll
    for (int r = 0; r < 4; ++r) {
      const float mnew = fmaxf(m_i[r], mloc[r]);
      alpha[r] = __builtin_amdgcn_exp2f(m_i[r] - mnew);
      m_i[r] = mnew;
      float sm = 0.f;
#pragma unroll
      for (int js = 0; js < 4; ++js) {
        const float p = __builtin_amdgcn_exp2f(sacc[js][r] - mnew);
        sacc[js][r] = p;
        sm += p;
      }
      rsum[r] = sm;
    }
#pragma unroll
    for (int d = 1; d < 16; d <<= 1)
#pragma unroll
      for (int r = 0; r < 4; ++r)
        rsum[r] += __shfl_xor(rsum[r], d, 64);
#pragma unroll
    for (int r = 0; r < 4; ++r)
      l_i[r] = l_i[r] * alpha[r] + rsum[r];
#pragma unroll
    for (int js = 0; js < 4; ++js)
#pragma unroll
      for (int r = 0; r < 4; ++r)
        oacc[js][r] *= alpha[r];

    // P: C-layout -> LDS -> A-layout (wave-private, in-order DS ops)
#pragma unroll
    for (int js = 0; js < 4; ++js)
#pragma unroll
      for (int r = 0; r < 4; ++r)
        Plds[w][q4 * 4 + r][js * 16 + l16] = f2bf(sacc[js][r]);

    asm volatile("" ::: "memory");

    const bf16x8 pf0 = *(const bf16x8*)&Plds[w][l16][q4 * 8];
    const bf16x8 pf1 = *(const bf16x8*)&Plds[w][l16][32 + q4 * 8];

#pragma unroll
    for (int js = 0; js < 4; ++js) {
      const bf16x8 vf0 = *(const bf16x8*)&Vs[js * 16 + l16][q4 * 8];
      const bf16x8 vf1 = *(const bf16x8*)&Vs[js * 16 + l16][32 + q4 * 8];
      oacc[js] = MFMA16(pf0, vf0, oacc[js]);
      oacc[js] = MFMA16(pf1, vf1, oacc[js]);
    }
  }

  // epilogue: concat-head layout ObB[s][h*64+dv]
#pragma unroll
  for (int js = 0; js < 4; ++js)
#pragma unroll
    for (int r = 0; r < 4; ++r) {
      const int q = q0 + w * 16 + q4 * 4 + r;
      const float v = oacc[js][r] / l_i[r];
      ObB[(size_t)q * 1024 + h * 64 + js * 16 + l16] = f2bf(v);
    }
}

// ---------------------------------------------------------------------------
// Output projection, ONE batch: ObB bf16 [2048][1024] x WoT bf16 [n][d]
// + bo(f32) -> outB FLOAT32 [2048][1024]
// ---------------------------------------------------------------------------
__global__ __launch_bounds__(256)
void oproj_kernel(const unsigned short* __restrict__ ObB,
                  const unsigned short* __restrict__ WoT,
                  const float* __restrict__ bo,
                  float* __restrict__ outB) {
  const int m0 = blockIdx.y * 128;
  const int n0 = blockIdx.x * 128;

  __shared__ __align__(16) unsigned short As[128][40];
  __shared__ __align__(16) unsigned short Bs[128][40];

  const int tid = threadIdx.x;
  const int lane = tid & 63, w = tid >> 6;
  const int q4 = lane >> 4, l16 = lane & 15;
  const int arow = tid >> 1, acol = (tid & 1) * 16;

  f32x4 acc[4][4] = {};

  for (int k0 = 0; k0 < 1024; k0 += 32) {
    __syncthreads();
    *(u32x4*)&As[arow][acol]     = *(const u32x4*)&ObB[(size_t)(m0 + arow) * 1024 + k0 + acol];
    *(u32x4*)&As[arow][acol + 8] = *(const u32x4*)&ObB[(size_t)(m0 + arow) * 1024 + k0 + acol + 8];
    *(u32x4*)&Bs[arow][acol]     = *(const u32x4*)&WoT[(size_t)(n0 + arow) * 1024 + k0 + acol];
    *(u32x4*)&Bs[arow][acol + 8] = *(const u32x4*)&WoT[(size_t)(n0 + arow) * 1024 + k0 + acol + 8];
    __syncthreads();

    bf16x8 af[4], bfr[4];
#pragma unroll
    for (int ms = 0; ms < 4; ++ms)
      af[ms] = *(const bf16x8*)&As[(w >> 1) * 64 + ms * 16 + l16][q4 * 8];
#pragma unroll
    for (int js = 0; js < 4; ++js)
      bfr[js] = *(const bf16x8*)&Bs[(w & 1) * 64 + js * 16 + l16][q4 * 8];
#pragma unroll
    for (int ms = 0; ms < 4; ++ms)
#pragma unroll
      for (int js = 0; js < 4; ++js)
        acc[ms][js] = MFMA16(af[ms], bfr[js], acc[ms][js]);
  }

#pragma unroll
  for (int js = 0; js < 4; ++js) {
    const int col = n0 + (w & 1) * 64 + js * 16 + l16;
    const float bias = bo[col];
#pragma unroll
    for (int ms = 0; ms < 4; ++ms)
#pragma unroll
      for (int r = 0; r < 4; ++r) {
        const int row = m0 + (w >> 1) * 64 + ms * 16 + q4 * 4 + r;
        outB[(size_t)row * 1024 + col] = acc[ms][js][r] + bias;  // f32 store
      }
  }
}

// ---------------------------------------------------------------------------
extern "C" void kernel_launch(void* const* d_in, const int* in_sizes, int n_in,
                              void* d_out, int out_size, void* d_ws, size_t ws_size,
                              hipStream_t stream) {
  const float* emb = (const float*)d_in[0];   // [4][2048][1024] f32
  const float* Wq  = (const float*)d_in[1];   // [16][1024][64]  f32
  const float* Wk  = (const float*)d_in[2];
  const float* Wv  = (const float*)d_in[3];
  const float* Wo  = (const float*)d_in[4];   // [1024][1024]    f32
  const float* bo  = (const float*)d_in[5];   // [1024]          f32
  float* out = (float*)d_out;                 // [4][2048][1024] f32

  char* ws = (char*)d_ws;
  const size_t MB = 1024 * 1024;
  // Peak workspace: 24 MB (< proven 29 MB bound).
  unsigned short* WqT = (unsigned short*)(ws + 0 * MB);    // 2 MB  [h][c][d] bf16
  unsigned short* WkT = (unsigned short*)(ws + 2 * MB);    // 2 MB
  unsigned short* WvT = (unsigned short*)(ws + 4 * MB);    // 2 MB
  unsigned short* WoT = (unsigned short*)(ws + 6 * MB);    // 2 MB  [n][d]
  unsigned short* Qb  = (unsigned short*)(ws + 8 * MB);    // 4 MB  [h][s][64] (per-batch)
  unsigned short* Kb  = (unsigned short*)(ws + 12 * MB);   // 4 MB
  unsigned short* Vtb = (unsigned short*)(ws + 16 * MB);   // 4 MB  [h][dv][s]
  unsigned short* ObB = (unsigned short*)(ws + 20 * MB);   // 4 MB  [s][1024] bf16 (per-batch)

  const dim3 tb(32, 8, 1);
  wtrans_kernel<<<dim3(2, 32, 16), tb, 0, stream>>>(Wq, WqT, 1024, 64);
  wtrans_kernel<<<dim3(2, 32, 16), tb, 0, stream>>>(Wk, WkT, 1024, 64);
  wtrans_kernel<<<dim3(2, 32, 16), tb, 0, stream>>>(Wv, WvT, 1024, 64);
  wtrans_kernel<<<dim3(32, 32, 1), tb, 0, stream>>>(Wo, WoT, 1024, 1024);

  for (int b = 0; b < 4; ++b) {
    const float* embB = emb + (size_t)b * 2048 * 1024;
    float* outB = out + (size_t)b * 2048 * 1024;
    qkv_kernel<<<dim3(8, 16, 3), 256, 0, stream>>>(embB, WqT, WkT, WvT, Qb, Kb, Vtb);
    flash_kernel<<<dim3(32, 16, 1), 256, 0, stream>>>(Qb, Kb, Vtb, ObB);
    oproj_kernel<<<dim3(8, 16, 1), 256, 0, stream>>>(ObB, WoT, bo, outB);
  }
}

// Round 9
// 492.529 us; speedup vs baseline: 1.4694x; 1.4694x over previous
//
#include <hip/hip_runtime.h>
#include <hip/hip_bf16.h>

// B=4, S=2048, D=1024, H=16, DK=DV=64. Inputs f32, output f32 (confirmed r8).
// MFMA math bf16 with f32 accum. Round 9: batch-merged launches (the r8
// per-batch loop serialized 4x at 11% occupancy). nb batches per group,
// chosen from ws_size: nb=4 (72 MB), nb=2 (40 MB), nb=1 (24 MB, proven).

typedef __attribute__((ext_vector_type(8))) short bf16x8;
typedef __attribute__((ext_vector_type(4))) float f32x4;
typedef __attribute__((ext_vector_type(4))) unsigned int u32x4;

#define MFMA16(a, b, c) __builtin_amdgcn_mfma_f32_16x16x32_bf16((a), (b), (c), 0, 0, 0)

#define LOG2E 1.44269504088896340736f
#define BIG_NEG (-3.0e38f)

__device__ __forceinline__ unsigned short f2bf(float f) {
  union { float f; unsigned int i; } x; x.f = f;
  unsigned int lsb = (x.i >> 16) & 1;
  x.i += 0x7fffu + lsb;  // RNE (finite inputs only)
  return (unsigned short)(x.i >> 16);
}

// ---------------------------------------------------------------------------
// Batched transpose + downconvert: in f32 [batch][R][C] -> out bf16 [batch][C][R]
// ---------------------------------------------------------------------------
__global__ void wtrans_kernel(const float* __restrict__ in,
                              unsigned short* __restrict__ out, int R, int C) {
  __shared__ unsigned short tile[32][33];
  const int bz = blockIdx.z;
  const int c0 = blockIdx.x * 32, r0 = blockIdx.y * 32;
  const float* ip = in + (size_t)bz * R * C;
  unsigned short* op = out + (size_t)bz * R * C;
  const int tx = threadIdx.x, ty = threadIdx.y;  // (32, 8)
#pragma unroll
  for (int i = 0; i < 32; i += 8)
    tile[ty + i][tx] = f2bf(ip[(size_t)(r0 + ty + i) * C + (c0 + tx)]);
  __syncthreads();
#pragma unroll
  for (int i = 0; i < 32; i += 8)
    op[(size_t)(c0 + ty + i) * R + (r0 + tx)] = tile[tx][ty + i];
}

// ---------------------------------------------------------------------------
// QKV projection, GROUP of nb batches: embG f32 [nb*2048][1024] x WtT bf16
// [h][c][d] -> Q,K bf16 [(b*16+h)][s][64], V transposed -> Vt [(b*16+h)][dv][s].
// Grid (8, 16*nb, 3). Tile 128x128, BK=32, 4 waves, 4x4 accs/wave.
// ---------------------------------------------------------------------------
__global__ __launch_bounds__(256)
void qkv_kernel(const float* __restrict__ embG,
                const unsigned short* __restrict__ WqT,
                const unsigned short* __restrict__ WkT,
                const unsigned short* __restrict__ WvT,
                unsigned short* __restrict__ QG,
                unsigned short* __restrict__ KG,
                unsigned short* __restrict__ VtG) {
  const int t = blockIdx.z;           // 0=Q, 1=K, 2=V
  const int m0 = blockIdx.y * 128;    // row in [0, nb*2048)
  const int n0 = blockIdx.x * 128;    // col in [0, 1024)
  const int b = m0 >> 11;             // local batch (tile never crosses: 2048%128==0)
  const int sloc = m0 & 2047;
  const unsigned short* Wt =
      (t == 0 ? WqT : (t == 1 ? WkT : WvT)) + (size_t)(n0 >> 6) * 64 * 1024;

  __shared__ __align__(16) unsigned short As[128][40];  // [m][k], +8 pad
  __shared__ __align__(16) unsigned short Bs[128][40];  // [n][k]

  const int tid = threadIdx.x;
  const int lane = tid & 63, w = tid >> 6;
  const int q4 = lane >> 4, l16 = lane & 15;
  const int arow = tid >> 1, acol = (tid & 1) * 16;

  f32x4 acc[4][4] = {};

  for (int k0 = 0; k0 < 1024; k0 += 32) {
    __syncthreads();
    {
      const float* erow = &embG[(size_t)(m0 + arow) * 1024 + k0 + acol];
      const float4 v0 = *(const float4*)&erow[0];
      const float4 v1 = *(const float4*)&erow[4];
      const float4 v2 = *(const float4*)&erow[8];
      const float4 v3 = *(const float4*)&erow[12];
      union { unsigned short u[8]; u32x4 v; } p0, p1;
      p0.u[0] = f2bf(v0.x); p0.u[1] = f2bf(v0.y); p0.u[2] = f2bf(v0.z); p0.u[3] = f2bf(v0.w);
      p0.u[4] = f2bf(v1.x); p0.u[5] = f2bf(v1.y); p0.u[6] = f2bf(v1.z); p0.u[7] = f2bf(v1.w);
      p1.u[0] = f2bf(v2.x); p1.u[1] = f2bf(v2.y); p1.u[2] = f2bf(v2.z); p1.u[3] = f2bf(v2.w);
      p1.u[4] = f2bf(v3.x); p1.u[5] = f2bf(v3.y); p1.u[6] = f2bf(v3.z); p1.u[7] = f2bf(v3.w);
      *(u32x4*)&As[arow][acol]     = p0.v;
      *(u32x4*)&As[arow][acol + 8] = p1.v;
    }
    *(u32x4*)&Bs[arow][acol]     = *(const u32x4*)&Wt[(size_t)arow * 1024 + k0 + acol];
    *(u32x4*)&Bs[arow][acol + 8] = *(const u32x4*)&Wt[(size_t)arow * 1024 + k0 + acol + 8];
    __syncthreads();

    // t==2: compute (W^T * emb^T) = V^T directly by swapping operand roles.
    const unsigned short (*PA)[40] = (t == 2) ? Bs : As;
    const unsigned short (*PB)[40] = (t == 2) ? As : Bs;

    bf16x8 af[4], bfr[4];
#pragma unroll
    for (int ms = 0; ms < 4; ++ms)
      af[ms] = *(const bf16x8*)&PA[(w >> 1) * 64 + ms * 16 + l16][q4 * 8];
#pragma unroll
    for (int js = 0; js < 4; ++js)
      bfr[js] = *(const bf16x8*)&PB[(w & 1) * 64 + js * 16 + l16][q4 * 8];
#pragma unroll
    for (int ms = 0; ms < 4; ++ms)
#pragma unroll
      for (int js = 0; js < 4; ++js)
        acc[ms][js] = MFMA16(af[ms], bfr[js], acc[ms][js]);
  }

  if (t < 2) {
    unsigned short* outp = (t == 0) ? QG : KG;
    const int h = (n0 >> 6) + (w & 1);
    const size_t hb = (size_t)(b * 16 + h) * 2048;
#pragma unroll
    for (int ms = 0; ms < 4; ++ms)
#pragma unroll
      for (int js = 0; js < 4; ++js) {
        const int c = js * 16 + l16;
#pragma unroll
        for (int r = 0; r < 4; ++r) {
          const int s = sloc + (w >> 1) * 64 + ms * 16 + q4 * 4 + r;
          outp[(hb + s) * 64 + c] = f2bf(acc[ms][js][r]);
        }
      }
  } else {
    const int h = (n0 >> 6) + (w >> 1);
    const size_t hb = (size_t)(b * 16 + h) * 64;
#pragma unroll
    for (int ms = 0; ms < 4; ++ms)
#pragma unroll
      for (int js = 0; js < 4; ++js) {
        const int s = sloc + (w & 1) * 64 + js * 16 + l16;
#pragma unroll
        for (int r = 0; r < 4; ++r) {
          const int c = ms * 16 + q4 * 4 + r;
          VtG[(hb + c) * 2048 + s] = f2bf(acc[ms][js][r]);
        }
      }
  }
}

// ---------------------------------------------------------------------------
// Flash attention, causal, GROUP of nb batches. Grid (32, 16*nb);
// blockIdx.y = local bh = b*16+h. Each wave owns 16 q-rows.
// ---------------------------------------------------------------------------
__global__ __launch_bounds__(256)
void flash_kernel(const unsigned short* __restrict__ QG,
                  const unsigned short* __restrict__ KG,
                  const unsigned short* __restrict__ VtG,
                  unsigned short* __restrict__ ObG) {
  const int bh = blockIdx.y;
  const int qt = (gridDim.x - 1) - blockIdx.x;  // longest blocks dispatch first
  const int q0 = qt * 64;
  const int tid = threadIdx.x;
  const int lane = tid & 63, w = tid >> 6;
  const int q4 = lane >> 4, l16 = lane & 15;

  const unsigned short* Qp = QG + ((size_t)bh * 2048 + q0 + w * 16) * 64;
  const unsigned short* Kp = KG + (size_t)bh * 2048 * 64;
  const unsigned short* Vp = VtG + (size_t)bh * 64 * 2048;

  const bf16x8 qf0 = *(const bf16x8*)&Qp[(size_t)l16 * 64 + q4 * 8];
  const bf16x8 qf1 = *(const bf16x8*)&Qp[(size_t)l16 * 64 + 32 + q4 * 8];

  __shared__ __align__(16) unsigned short Ks[64][72];        // [s][d]
  __shared__ __align__(16) unsigned short Vs[64][72];        // [dv][s]
  __shared__ __align__(16) unsigned short Plds[4][16][72];   // per-wave P round-trip

  f32x4 oacc[4] = {};
  float m_i[4], l_i[4];
#pragma unroll
  for (int r = 0; r < 4; ++r) { m_i[r] = BIG_NEG; l_i[r] = 0.f; }

  const float sscale = 0.125f * LOG2E;  // softmax in exp2 domain

  for (int j0 = 0; j0 <= q0; j0 += 64) {
    __syncthreads();
#pragma unroll
    for (int i = 0; i < 2; ++i) {
      const int r = (tid >> 3) + i * 32, c = (tid & 7) * 8;
      *(u32x4*)&Ks[r][c] = *(const u32x4*)&Kp[(size_t)(j0 + r) * 64 + c];
      *(u32x4*)&Vs[r][c] = *(const u32x4*)&Vp[(size_t)r * 2048 + j0 + c];
    }
    __syncthreads();

    // S = Q K^T for 16 q-rows x 64 k-cols
    f32x4 sacc[4] = {};
#pragma unroll
    for (int js = 0; js < 4; ++js) {
      const bf16x8 kf0 = *(const bf16x8*)&Ks[js * 16 + l16][q4 * 8];
      const bf16x8 kf1 = *(const bf16x8*)&Ks[js * 16 + l16][32 + q4 * 8];
      sacc[js] = MFMA16(qf0, kf0, sacc[js]);
      sacc[js] = MFMA16(qf1, kf1, sacc[js]);
    }

    float mloc[4];
#pragma unroll
    for (int r = 0; r < 4; ++r) mloc[r] = BIG_NEG;
    if (j0 == q0) {
#pragma unroll
      for (int js = 0; js < 4; ++js) {
        const int col = js * 16 + l16;
#pragma unroll
        for (int r = 0; r < 4; ++r) {
          const int qrel = w * 16 + q4 * 4 + r;
          float v = sacc[js][r] * sscale;
          if (col > qrel) v = BIG_NEG;
          sacc[js][r] = v;
          mloc[r] = fmaxf(mloc[r], v);
        }
      }
    } else {
#pragma unroll
      for (int js = 0; js < 4; ++js)
#pragma unroll
        for (int r = 0; r < 4; ++r) {
          const float v = sacc[js][r] * sscale;
          sacc[js][r] = v;
          mloc[r] = fmaxf(mloc[r], v);
        }
    }

#pragma unroll
    for (int d = 1; d < 16; d <<= 1)
#pragma unroll
      for (int r = 0; r < 4; ++r)
        mloc[r] = fmaxf(mloc[r], __shfl_xor(mloc[r], d, 64));

    float alpha[4], rsum[4];
#pragma unroll
    for (int r = 0; r < 4; ++r) {
      const float mnew = fmaxf(m_i[r], mloc[r]);
      alpha[r] = __builtin_amdgcn_exp2f(m_i[r] - mnew);
      m_i[r] = mnew;
      float sm = 0.f;
#pragma unroll
      for (int js = 0; js < 4; ++js) {
        const float p = __builtin_amdgcn_exp2f(sacc[js][r] - mnew);
        sacc[js][r] = p;
        sm += p;
      }
      rsum[r] = sm;
    }
#pragma unroll
    for (int d = 1; d < 16; d <<= 1)
#pragma unroll
      for (int r = 0; r < 4; ++r)
        rsum[r] += __shfl_xor(rsum[r], d, 64);
#pragma unroll
    for (int r = 0; r < 4; ++r)
      l_i[r] = l_i[r] * alpha[r] + rsum[r];
#pragma unroll
    for (int js = 0; js < 4; ++js)
#pragma unroll
      for (int r = 0; r < 4; ++r)
        oacc[js][r] *= alpha[r];

    // P: C-layout -> LDS -> A-layout (wave-private, in-order DS ops)
#pragma unroll
    for (int js = 0; js < 4; ++js)
#pragma unroll
      for (int r = 0; r < 4; ++r)
        Plds[w][q4 * 4 + r][js * 16 + l16] = f2bf(sacc[js][r]);

    asm volatile("" ::: "memory");

    const bf16x8 pf0 = *(const bf16x8*)&Plds[w][l16][q4 * 8];
    const bf16x8 pf1 = *(const bf16x8*)&Plds[w][l16][32 + q4 * 8];

#pragma unroll
    for (int js = 0; js < 4; ++js) {
      const bf16x8 vf0 = *(const bf16x8*)&Vs[js * 16 + l16][q4 * 8];
      const bf16x8 vf1 = *(const bf16x8*)&Vs[js * 16 + l16][32 + q4 * 8];
      oacc[js] = MFMA16(pf0, vf0, oacc[js]);
      oacc[js] = MFMA16(pf1, vf1, oacc[js]);
    }
  }

  // epilogue: concat-head layout ObG[b][s][h*64+dv]
  const int b = bh >> 4, h = bh & 15;
#pragma unroll
  for (int js = 0; js < 4; ++js)
#pragma unroll
    for (int r = 0; r < 4; ++r) {
      const int q = q0 + w * 16 + q4 * 4 + r;
      const float v = oacc[js][r] / l_i[r];
      ObG[((size_t)b * 2048 + q) * 1024 + h * 64 + js * 16 + l16] = f2bf(v);
    }
}

// ---------------------------------------------------------------------------
// Output projection, GROUP: ObG bf16 [nb*2048][1024] x WoT bf16 [n][d]
// + bo(f32) -> outG f32 [nb*2048][1024].  Grid (8, 16*nb).
// ---------------------------------------------------------------------------
__global__ __launch_bounds__(256)
void oproj_kernel(const unsigned short* __restrict__ ObG,
                  const unsigned short* __restrict__ WoT,
                  const float* __restrict__ bo,
                  float* __restrict__ outG) {
  const int m0 = blockIdx.y * 128;
  const int n0 = blockIdx.x * 128;

  __shared__ __align__(16) unsigned short As[128][40];
  __shared__ __align__(16) unsigned short Bs[128][40];

  const int tid = threadIdx.x;
  const int lane = tid & 63, w = tid >> 6;
  const int q4 = lane >> 4, l16 = lane & 15;
  const int arow = tid >> 1, acol = (tid & 1) * 16;

  f32x4 acc[4][4] = {};

  for (int k0 = 0; k0 < 1024; k0 += 32) {
    __syncthreads();
    *(u32x4*)&As[arow][acol]     = *(const u32x4*)&ObG[(size_t)(m0 + arow) * 1024 + k0 + acol];
    *(u32x4*)&As[arow][acol + 8] = *(const u32x4*)&ObG[(size_t)(m0 + arow) * 1024 + k0 + acol + 8];
    *(u32x4*)&Bs[arow][acol]     = *(const u32x4*)&WoT[(size_t)(n0 + arow) * 1024 + k0 + acol];
    *(u32x4*)&Bs[arow][acol + 8] = *(const u32x4*)&WoT[(size_t)(n0 + arow) * 1024 + k0 + acol + 8];
    __syncthreads();

    bf16x8 af[4], bfr[4];
#pragma unroll
    for (int ms = 0; ms < 4; ++ms)
      af[ms] = *(const bf16x8*)&As[(w >> 1) * 64 + ms * 16 + l16][q4 * 8];
#pragma unroll
    for (int js = 0; js < 4; ++js)
      bfr[js] = *(const bf16x8*)&Bs[(w & 1) * 64 + js * 16 + l16][q4 * 8];
#pragma unroll
    for (int ms = 0; ms < 4; ++ms)
#pragma unroll
      for (int js = 0; js < 4; ++js)
        acc[ms][js] = MFMA16(af[ms], bfr[js], acc[ms][js]);
  }

#pragma unroll
  for (int js = 0; js < 4; ++js) {
    const int col = n0 + (w & 1) * 64 + js * 16 + l16;
    const float bias = bo[col];
#pragma unroll
    for (int ms = 0; ms < 4; ++ms)
#pragma unroll
      for (int r = 0; r < 4; ++r) {
        const int row = m0 + (w >> 1) * 64 + ms * 16 + q4 * 4 + r;
        outG[(size_t)row * 1024 + col] = acc[ms][js][r] + bias;  // f32 store
      }
  }
}

// ---------------------------------------------------------------------------
extern "C" void kernel_launch(void* const* d_in, const int* in_sizes, int n_in,
                              void* d_out, int out_size, void* d_ws, size_t ws_size,
                              hipStream_t stream) {
  const float* emb = (const float*)d_in[0];   // [4][2048][1024] f32
  const float* Wq  = (const float*)d_in[1];   // [16][1024][64]  f32
  const float* Wk  = (const float*)d_in[2];
  const float* Wv  = (const float*)d_in[3];
  const float* Wo  = (const float*)d_in[4];   // [1024][1024]    f32
  const float* bo  = (const float*)d_in[5];   // [1024]          f32
  float* out = (float*)d_out;                 // [4][2048][1024] f32

  char* ws = (char*)d_ws;
  const size_t MB = 1024 * 1024;

  // group size: nb batches per pipeline pass. ws need = 8 + 16*nb MB.
  const int nb = (ws_size >= 72 * MB) ? 4 : (ws_size >= 40 * MB) ? 2 : 1;

  unsigned short* WqT = (unsigned short*)(ws + 0 * MB);              // 2 MB [h][c][d]
  unsigned short* WkT = (unsigned short*)(ws + 2 * MB);              // 2 MB
  unsigned short* WvT = (unsigned short*)(ws + 4 * MB);              // 2 MB
  unsigned short* WoT = (unsigned short*)(ws + 6 * MB);              // 2 MB [n][d]
  unsigned short* QG  = (unsigned short*)(ws + 8 * MB);              // 4*nb MB
  unsigned short* KG  = (unsigned short*)(ws + (8 + 4 * nb) * MB);   // 4*nb MB
  unsigned short* VtG = (unsigned short*)(ws + (8 + 8 * nb) * MB);   // 4*nb MB
  unsigned short* ObG = (unsigned short*)(ws + (8 + 12 * nb) * MB);  // 4*nb MB

  const dim3 tb(32, 8, 1);
  wtrans_kernel<<<dim3(2, 32, 16), tb, 0, stream>>>(Wq, WqT, 1024, 64);
  wtrans_kernel<<<dim3(2, 32, 16), tb, 0, stream>>>(Wk, WkT, 1024, 64);
  wtrans_kernel<<<dim3(2, 32, 16), tb, 0, stream>>>(Wv, WvT, 1024, 64);
  wtrans_kernel<<<dim3(32, 32, 1), tb, 0, stream>>>(Wo, WoT, 1024, 1024);

  for (int g = 0; g < 4; g += nb) {
    const float* embG = emb + (size_t)g * 2048 * 1024;
    float* outG = out + (size_t)g * 2048 * 1024;
    qkv_kernel<<<dim3(8, 16 * nb, 3), 256, 0, stream>>>(embG, WqT, WkT, WvT, QG, KG, VtG);
    flash_kernel<<<dim3(32, 16 * nb), 256, 0, stream>>>(QG, KG, VtG, ObG);
    oproj_kernel<<<dim3(8, 16 * nb), 256, 0, stream>>>(ObG, WoT, bo, outG);
  }
}